// Round 11
// baseline (318.065 us; speedup 1.0000x reference)
//
#include <hip/hip_runtime.h>
#include <cstdint>
#include <cstddef>

#define GN 16384          // nodes
#define GF 64             // features
#define NW (GN / 32)      // 512 words per column

typedef __bf16 bf16x8 __attribute__((ext_vector_type(8)));
typedef float f32x4 __attribute__((ext_vector_type(4)));
typedef unsigned int u32x4 __attribute__((ext_vector_type(4)));

// R2/R6/R7-validated cheap decode.
__device__ __forceinline__ bf16x8 decode8(unsigned int b) {
  unsigned int t = (b & 0xffu) * 0x8001u;
  u32x4 r;
  r[0] = (t & 0x00010001u) * 0x3F80u;
  r[1] = ((t >> 2) & 0x00010001u) * 0x3F80u;
  r[2] = ((t >> 4) & 0x00010001u) * 0x3F80u;
  r[3] = ((t >> 6) & 0x00010001u) * 0x3F80u;
  return __builtin_bit_cast(bf16x8, r);
}

__device__ __forceinline__ unsigned short f2bf(float v) {  // RNE f32->bf16
  unsigned int u = __builtin_bit_cast(unsigned int, v);
  u += 0x7fffu + ((u >> 16) & 1u);
  return (unsigned short)(u >> 16);
}

__device__ __forceinline__ float bf2f(unsigned short s) {
  return __builtin_bit_cast(float, (unsigned int)s << 16);
}

// ---------------------------------------------------------------------------
// K1 v5: TRANSPOSED layout packedT[w][c] (word-major), CONTIGUOUS streaming.
// Grid 1024 = 512 row-slabs (32 rows = 1 word) x 2 col-halves; 4 blocks/CU.
// Per row the block reads one contiguous 32 KB slice (8 x 4KB per-cc bursts),
// marching rows sequentially. Stores: 8 contiguous 4 KB wave-writes.
// Bit semantics identical to prior rounds: packedT[w][c] bit b = adj[w*32+b][c].
// ---------------------------------------------------------------------------
__global__ __launch_bounds__(256) void k_pack(const float* __restrict__ adj,
                                              float* __restrict__ deg,
                                              unsigned int* __restrict__ packedT) {
  const int jb = (int)blockIdx.x >> 1;             // 32-row slab = word index
  const int ch = (int)blockIdx.x & 1;              // column half
  const int j0 = jb * 32;
  const int c0 = ch * 8192 + (int)threadIdx.x * 4; // +cc*1024 per chunk

  unsigned int wb[8][4];
#pragma unroll
  for (int cc = 0; cc < 8; ++cc)
#pragma unroll
    for (int q = 0; q < 4; ++q) wb[cc][q] = 0;

  for (int b = 0; b < 32; ++b) {
    const float* rowp = adj + (size_t)(j0 + b) * GN + c0;
    const unsigned int m = 1u << b;
#pragma unroll
    for (int cc = 0; cc < 8; ++cc) {
      f32x4 a = *(const f32x4*)(rowp + cc * 1024);
      if (a.x != 0.f) wb[cc][0] |= m;
      if (a.y != 0.f) wb[cc][1] |= m;
      if (a.z != 0.f) wb[cc][2] |= m;
      if (a.w != 0.f) wb[cc][3] |= m;
    }
  }

  unsigned int* dst = packedT + (size_t)jb * GN + c0;
#pragma unroll
  for (int cc = 0; cc < 8; ++cc) {
    u32x4 v = {wb[cc][0], wb[cc][1], wb[cc][2], wb[cc][3]};
    *(u32x4*)(dst + cc * 1024) = v;
  }
#pragma unroll
  for (int cc = 0; cc < 8; ++cc) {
    atomicAdd(&deg[c0 + cc * 1024 + 0], (float)__popc(wb[cc][0]));
    atomicAdd(&deg[c0 + cc * 1024 + 1], (float)__popc(wb[cc][1]));
    atomicAdd(&deg[c0 + cc * 1024 + 2], (float)__popc(wb[cc][2]));
    atomicAdd(&deg[c0 + cc * 1024 + 3], (float)__popc(wb[cc][3]));
  }
}

// ---------------------------------------------------------------------------
// K2 (byte-identical to R4-R10).
// ---------------------------------------------------------------------------
__global__ __launch_bounds__(256) void k_z(const float* __restrict__ x,
                                           const float* __restrict__ W,
                                           const float* __restrict__ deg,
                                           float* __restrict__ dinv,
                                           unsigned short* __restrict__ z_rm,
                                           unsigned short* __restrict__ z2) {
  __shared__ float Wl[64][64];
  __shared__ float xl[64][64];
  const int tid = threadIdx.x;
  const int f = tid & 63;
  const int w = tid >> 6;
  const int rowB = blockIdx.x * 64;

  for (int idx = tid; idx < 4096; idx += 256) {
    Wl[idx >> 6][idx & 63] = W[idx];
    xl[idx >> 6][idx & 63] = x[(size_t)rowB * 64 + idx];
  }
  __syncthreads();

  float acc[16];
#pragma unroll
  for (int r = 0; r < 16; ++r) acc[r] = 0.f;
  for (int k = 0; k < 64; ++k) {
    float wk = Wl[k][f];
#pragma unroll
    for (int r = 0; r < 16; ++r) acc[r] = fmaf(xl[w * 16 + r][k], wk, acc[r]);
  }

  const int row0 = rowB + w * 16;
  if (f < 16) {
    int row = row0 + f;
    dinv[row] = 1.0f / sqrtf(deg[row] + 1.0f);
  }

  unsigned short zs[16];
#pragma unroll
  for (int r = 0; r < 16; ++r) {
    int row = row0 + r;
    float di = 1.0f / sqrtf(deg[row] + 1.0f);
    unsigned short zb = f2bf(di * acc[r]);
    zs[r] = zb;
    z_rm[(size_t)row * GF + f] = zb;
  }
  unsigned int p[8];
#pragma unroll
  for (int i = 0; i < 8; ++i)
    p[i] = (unsigned int)zs[2 * i] | ((unsigned int)zs[2 * i + 1] << 16);
  char* dst = (char*)z2 + (size_t)((rowB >> 5) + (w >> 1)) * 4096 + f * 64 + (w & 1) * 32;
  u32x4 lo = {p[0], p[1], p[2], p[3]};
  u32x4 hi = {p[4], p[5], p[6], p[7]};
  *(u32x4*)dst = lo;
  *(u32x4*)(dst + 16) = hi;
}

// ---------------------------------------------------------------------------
// K3 v7: EXACT R7 v5 structure/numerics; ONLY bits addressing changed to the
// transposed packedT[w][c] layout: 4 scalar dword loads per group per iter
// (lanes 0-15 read 64 B contiguous; kb groups broadcast the same words).
// ---------------------------------------------------------------------------
__global__ __launch_bounds__(512) void k_spmm(const unsigned int* __restrict__ packedT,
                                              const unsigned short* __restrict__ z2,
                                              const unsigned short* __restrict__ z_rm,
                                              const float* __restrict__ dinv,
                                              const float* __restrict__ bias,
                                              float* __restrict__ out) {
  __shared__ float red[4][64][64];  // 64 KB
  const int i0 = blockIdx.x * 64;
  const int tid = threadIdx.x;
  const int wid = tid >> 6, lane = tid & 63;
  const int lrow = lane & 15, kb = lane >> 4;
  const int sh = kb * 8;

  f32x4 acc[4][4];
#pragma unroll
  for (int m = 0; m < 4; ++m)
#pragma unroll
    for (int n = 0; n < 4; ++n) acc[m][n] = (f32x4){0.f, 0.f, 0.f, 0.f};

  // bits base: word wid*64, col i0 + g*16 + lrow  (g*16 = +0/+16/+32/+48)
  const unsigned int* pw = packedT + (size_t)(wid * 64) * GN + i0 + lrow;
  const char* zbase = (const char*)z2 + (size_t)(wid * 64) * 4096 + lrow * 64 + kb * 16;

  // prologue: first 4 words + first z chunk
  bf16x8 cur0 = *(const bf16x8*)(zbase + 0 * 1024);
  bf16x8 cur1 = *(const bf16x8*)(zbase + 1 * 1024);
  bf16x8 cur2 = *(const bf16x8*)(zbase + 2 * 1024);
  bf16x8 cur3 = *(const bf16x8*)(zbase + 3 * 1024);
  u32x4 bits0, bits1, bits2, bits3;
#pragma unroll
  for (int s = 0; s < 4; ++s) {
    const unsigned int* ps = pw + (size_t)s * GN;
    bits0[s] = ps[0];
    bits1[s] = ps[16];
    bits2[s] = ps[32];
    bits3[s] = ps[48];
  }
  const unsigned int* pnext = pw + (size_t)4 * GN;

  for (int it = 0; it < 16; ++it) {
    // prefetch next iter's 4 words (tail reads land in 256 KB ws slack)
    u32x4 nb0, nb1, nb2, nb3;
#pragma unroll
    for (int s = 0; s < 4; ++s) {
      const unsigned int* ps = pnext + (size_t)s * GN;
      nb0[s] = ps[0];
      nb1[s] = ps[16];
      nb2[s] = ps[32];
      nb3[s] = ps[48];
    }
#pragma unroll
    for (int s = 0; s < 4; ++s) {
      const char* zn = zbase + (s + 1) * 4096;
      bf16x8 n0 = *(const bf16x8*)(zn + 0 * 1024);
      bf16x8 n1 = *(const bf16x8*)(zn + 1 * 1024);
      bf16x8 n2 = *(const bf16x8*)(zn + 2 * 1024);
      bf16x8 n3 = *(const bf16x8*)(zn + 3 * 1024);

      bf16x8 a0 = decode8(bits0[s] >> sh);
      acc[0][0] = __builtin_amdgcn_mfma_f32_16x16x32_bf16(a0, cur0, acc[0][0], 0, 0, 0);
      acc[0][1] = __builtin_amdgcn_mfma_f32_16x16x32_bf16(a0, cur1, acc[0][1], 0, 0, 0);
      acc[0][2] = __builtin_amdgcn_mfma_f32_16x16x32_bf16(a0, cur2, acc[0][2], 0, 0, 0);
      acc[0][3] = __builtin_amdgcn_mfma_f32_16x16x32_bf16(a0, cur3, acc[0][3], 0, 0, 0);
      bf16x8 a1 = decode8(bits1[s] >> sh);
      acc[1][0] = __builtin_amdgcn_mfma_f32_16x16x32_bf16(a1, cur0, acc[1][0], 0, 0, 0);
      acc[1][1] = __builtin_amdgcn_mfma_f32_16x16x32_bf16(a1, cur1, acc[1][1], 0, 0, 0);
      acc[1][2] = __builtin_amdgcn_mfma_f32_16x16x32_bf16(a1, cur2, acc[1][2], 0, 0, 0);
      acc[1][3] = __builtin_amdgcn_mfma_f32_16x16x32_bf16(a1, cur3, acc[1][3], 0, 0, 0);
      bf16x8 a2 = decode8(bits2[s] >> sh);
      acc[2][0] = __builtin_amdgcn_mfma_f32_16x16x32_bf16(a2, cur0, acc[2][0], 0, 0, 0);
      acc[2][1] = __builtin_amdgcn_mfma_f32_16x16x32_bf16(a2, cur1, acc[2][1], 0, 0, 0);
      acc[2][2] = __builtin_amdgcn_mfma_f32_16x16x32_bf16(a2, cur2, acc[2][2], 0, 0, 0);
      acc[2][3] = __builtin_amdgcn_mfma_f32_16x16x32_bf16(a2, cur3, acc[2][3], 0, 0, 0);
      bf16x8 a3 = decode8(bits3[s] >> sh);
      acc[3][0] = __builtin_amdgcn_mfma_f32_16x16x32_bf16(a3, cur0, acc[3][0], 0, 0, 0);
      acc[3][1] = __builtin_amdgcn_mfma_f32_16x16x32_bf16(a3, cur1, acc[3][1], 0, 0, 0);
      acc[3][2] = __builtin_amdgcn_mfma_f32_16x16x32_bf16(a3, cur2, acc[3][2], 0, 0, 0);
      acc[3][3] = __builtin_amdgcn_mfma_f32_16x16x32_bf16(a3, cur3, acc[3][3], 0, 0, 0);

      cur0 = n0; cur1 = n1; cur2 = n2; cur3 = n3;
    }
    bits0 = nb0; bits1 = nb1; bits2 = nb2; bits3 = nb3;
    pnext += (size_t)4 * GN;
    zbase += 16384;
  }

  if (wid < 4) {
#pragma unroll
    for (int m = 0; m < 4; ++m)
#pragma unroll
      for (int n = 0; n < 4; ++n)
#pragma unroll
        for (int r = 0; r < 4; ++r)
          red[wid][m * 16 + kb * 4 + r][n * 16 + lrow] = acc[m][n][r];
  }
  __syncthreads();
  if (wid >= 4) {
#pragma unroll
    for (int m = 0; m < 4; ++m)
#pragma unroll
      for (int n = 0; n < 4; ++n)
#pragma unroll
        for (int r = 0; r < 4; ++r)
          red[wid - 4][m * 16 + kb * 4 + r][n * 16 + lrow] += acc[m][n][r];
  }
  __syncthreads();

  const int c = tid & 63;
  const int rg = tid >> 6;
  const float bc = bias[c];
#pragma unroll
  for (int rr = 0; rr < 8; ++rr) {
    int r = rg * 8 + rr;
    int i = i0 + r;
    float s = red[0][r][c] + red[1][r][c] + red[2][r][c] + red[3][r][c];
    float o = dinv[i] * (s + bf2f(z_rm[(size_t)i * GF + c])) + bc;
    out[(size_t)i * GF + c] = fmaxf(o, 0.f);
  }
}

// ---------------------------------------------------------------------------
extern "C" void kernel_launch(void* const* d_in, const int* in_sizes, int n_in,
                              void* d_out, int out_size, void* d_ws, size_t ws_size,
                              hipStream_t stream) {
  const float* x = (const float*)d_in[0];
  const float* adj = (const float*)d_in[1];
  const float* W = (const float*)d_in[2];
  const float* bias = (const float*)d_in[3];
  float* out = (float*)d_out;

  char* ws = (char*)d_ws;
  float* deg = (float*)ws;                                          // 64 KB
  float* dinv = (float*)(ws + 65536);                               // 64 KB
  unsigned short* z_rm = (unsigned short*)(ws + 131072);            // 2 MB
  unsigned short* z2 = (unsigned short*)(ws + 131072 + 2097152);    // 2 MB chunk-tiled
  unsigned int* packedT = (unsigned int*)(ws + 131072 + 4194304);   // 32 MB + 256 KB slack
  // need: 131072 + 4 MB + 32 MB + 256 KB slack (spmm tail word-prefetch)
  if (ws_size < 38141952u) return;

  hipMemsetAsync(deg, 0, GN * sizeof(float), stream);
  k_pack<<<dim3(1024), dim3(256), 0, stream>>>(adj, deg, packedT);
  k_z<<<dim3(GN / 64), dim3(256), 0, stream>>>(x, W, deg, dinv, z_rm, z2);
  k_spmm<<<dim3(GN / 64), dim3(512), 0, stream>>>(packedT, z2, z_rm, dinv, bias, out);
}

// Round 12
// 282.818 us; speedup vs baseline: 1.1246x; 1.1246x over previous
//
#include <hip/hip_runtime.h>
#include <cstdint>
#include <cstddef>

#define GN 16384          // nodes
#define GF 64             // features
#define NW (GN / 32)      // 512 dwords per packed bit-row

typedef __bf16 bf16x8 __attribute__((ext_vector_type(8)));
typedef float f32x4 __attribute__((ext_vector_type(4)));
typedef unsigned int u32x4 __attribute__((ext_vector_type(4)));

// R2/R6/R7-validated cheap decode.
__device__ __forceinline__ bf16x8 decode8(unsigned int b) {
  unsigned int t = (b & 0xffu) * 0x8001u;
  u32x4 r;
  r[0] = (t & 0x00010001u) * 0x3F80u;
  r[1] = ((t >> 2) & 0x00010001u) * 0x3F80u;
  r[2] = ((t >> 4) & 0x00010001u) * 0x3F80u;
  r[3] = ((t >> 6) & 0x00010001u) * 0x3F80u;
  return __builtin_bit_cast(bf16x8, r);
}

__device__ __forceinline__ unsigned short f2bf(float v) {  // RNE f32->bf16
  unsigned int u = __builtin_bit_cast(unsigned int, v);
  u += 0x7fffu + ((u >> 16) & 1u);
  return (unsigned short)(u >> 16);
}

__device__ __forceinline__ float bf2f(unsigned short s) {
  return __builtin_bit_cast(float, (unsigned int)s << 16);
}

// ---------------------------------------------------------------------------
// K1 (byte-identical to R7/R8/R10-base): contiguous 64 B per-column stores.
// ---------------------------------------------------------------------------
__global__ __launch_bounds__(256) void k_pack(const float* __restrict__ adj,
                                              float* __restrict__ deg,
                                              unsigned int* __restrict__ packed) {
  const int cb = blockIdx.x >> 5;
  const int jb = blockIdx.x & 31;
  const int col0 = cb * 1024 + threadIdx.x * 4;
  const int j0 = jb * 512;
  int cnt0 = 0, cnt1 = 0, cnt2 = 0, cnt3 = 0;

  u32x4 vv0[4], vv1[4], vv2[4], vv3[4];

#pragma unroll
  for (int seg = 0; seg < 4; ++seg) {
#pragma unroll
    for (int q = 0; q < 4; ++q) {
      unsigned int w0 = 0, w1 = 0, w2 = 0, w3 = 0;
      const float* base = adj + (size_t)(j0 + seg * 128 + q * 32) * GN + col0;
#pragma unroll 8
      for (int b = 0; b < 32; ++b) {
        f32x4 a = *(const f32x4*)(base + (size_t)b * GN);
        unsigned int m = 1u << b;
        if (a.x != 0.f) w0 |= m;
        if (a.y != 0.f) w1 |= m;
        if (a.z != 0.f) w2 |= m;
        if (a.w != 0.f) w3 |= m;
      }
      vv0[seg][q] = w0; vv1[seg][q] = w1; vv2[seg][q] = w2; vv3[seg][q] = w3;
      cnt0 += __popc(w0); cnt1 += __popc(w1); cnt2 += __popc(w2); cnt3 += __popc(w3);
    }
  }
  unsigned int* p0 = packed + (size_t)(col0 + 0) * NW + (size_t)jb * 16;
  unsigned int* p1 = packed + (size_t)(col0 + 1) * NW + (size_t)jb * 16;
  unsigned int* p2 = packed + (size_t)(col0 + 2) * NW + (size_t)jb * 16;
  unsigned int* p3 = packed + (size_t)(col0 + 3) * NW + (size_t)jb * 16;
#pragma unroll
  for (int seg = 0; seg < 4; ++seg) *(u32x4*)(p0 + seg * 4) = vv0[seg];
#pragma unroll
  for (int seg = 0; seg < 4; ++seg) *(u32x4*)(p1 + seg * 4) = vv1[seg];
#pragma unroll
  for (int seg = 0; seg < 4; ++seg) *(u32x4*)(p2 + seg * 4) = vv2[seg];
#pragma unroll
  for (int seg = 0; seg < 4; ++seg) *(u32x4*)(p3 + seg * 4) = vv3[seg];

  atomicAdd(&deg[col0 + 0], (float)cnt0);
  atomicAdd(&deg[col0 + 1], (float)cnt1);
  atomicAdd(&deg[col0 + 2], (float)cnt2);
  atomicAdd(&deg[col0 + 3], (float)cnt3);
}

// ---------------------------------------------------------------------------
// K2 (byte-identical to R4-R11).
// ---------------------------------------------------------------------------
__global__ __launch_bounds__(256) void k_z(const float* __restrict__ x,
                                           const float* __restrict__ W,
                                           const float* __restrict__ deg,
                                           float* __restrict__ dinv,
                                           unsigned short* __restrict__ z_rm,
                                           unsigned short* __restrict__ z2) {
  __shared__ float Wl[64][64];
  __shared__ float xl[64][64];
  const int tid = threadIdx.x;
  const int f = tid & 63;
  const int w = tid >> 6;
  const int rowB = blockIdx.x * 64;

  for (int idx = tid; idx < 4096; idx += 256) {
    Wl[idx >> 6][idx & 63] = W[idx];
    xl[idx >> 6][idx & 63] = x[(size_t)rowB * 64 + idx];
  }
  __syncthreads();

  float acc[16];
#pragma unroll
  for (int r = 0; r < 16; ++r) acc[r] = 0.f;
  for (int k = 0; k < 64; ++k) {
    float wk = Wl[k][f];
#pragma unroll
    for (int r = 0; r < 16; ++r) acc[r] = fmaf(xl[w * 16 + r][k], wk, acc[r]);
  }

  const int row0 = rowB + w * 16;
  if (f < 16) {
    int row = row0 + f;
    dinv[row] = 1.0f / sqrtf(deg[row] + 1.0f);
  }

  unsigned short zs[16];
#pragma unroll
  for (int r = 0; r < 16; ++r) {
    int row = row0 + r;
    float di = 1.0f / sqrtf(deg[row] + 1.0f);
    unsigned short zb = f2bf(di * acc[r]);
    zs[r] = zb;
    z_rm[(size_t)row * GF + f] = zb;
  }
  unsigned int p[8];
#pragma unroll
  for (int i = 0; i < 8; ++i)
    p[i] = (unsigned int)zs[2 * i] | ((unsigned int)zs[2 * i + 1] << 16);
  char* dst = (char*)z2 + (size_t)((rowB >> 5) + (w >> 1)) * 4096 + f * 64 + (w & 1) * 32;
  u32x4 lo = {p[0], p[1], p[2], p[3]};
  u32x4 hi = {p[4], p[5], p[6], p[7]};
  *(u32x4*)dst = lo;
  *(u32x4*)(dst + 16) = hi;
}

// ---------------------------------------------------------------------------
// K3 v8: COL-SPLIT ACROSS BLOCKS. Grid 512 = 256 row-tiles x 2 col-halves;
// block = 64 rows x 32 cols, 8 waves = 8 K-eighths, acc[4][2] (32 VGPR).
// __launch_bounds__(512,4): 2 blocks/CU -> 4 waves/SIMD (2x latency hiding
// vs R7; this is what R6 failed to test -- its grid stayed 256).
// Per wave/step: 4 decodes + 2 z-loads + 8 MFMA. Chip z2 L2 traffic unchanged
// (each block reads only its col-half of every chunk); bits HBM doubles
// (64 MB, overlapped). K-partial grouping + add order identical to R7 ->
// absmax must stay exactly 2.441406e-4.
// ---------------------------------------------------------------------------
__global__ __launch_bounds__(512, 4) void k_spmm(const unsigned int* __restrict__ packed,
                                                 const unsigned short* __restrict__ z2,
                                                 const unsigned short* __restrict__ z_rm,
                                                 const float* __restrict__ dinv,
                                                 const float* __restrict__ bias,
                                                 float* __restrict__ out) {
  __shared__ float red[4][64][32];  // 32 KB
  const int i0 = ((int)blockIdx.x >> 1) * 64;
  const int h = (int)blockIdx.x & 1;  // column half
  const int tid = threadIdx.x;
  const int wid = tid >> 6, lane = tid & 63;
  const int lrow = lane & 15, kb = lane >> 4;
  const int sh = kb * 8;

  f32x4 acc[4][2];
#pragma unroll
  for (int m = 0; m < 4; ++m)
#pragma unroll
    for (int n = 0; n < 2; ++n) acc[m][n] = (f32x4){0.f, 0.f, 0.f, 0.f};

  const unsigned int* pr0 = packed + (size_t)(i0 + 0 * 16 + lrow) * NW + wid * 64;
  const unsigned int* pr1 = packed + (size_t)(i0 + 1 * 16 + lrow) * NW + wid * 64;
  const unsigned int* pr2 = packed + (size_t)(i0 + 2 * 16 + lrow) * NW + wid * 64;
  const unsigned int* pr3 = packed + (size_t)(i0 + 3 * 16 + lrow) * NW + wid * 64;
  // chunk = wid*64 + it*4 + s; within chunk: col (h*32 + n*16 + lrow), quad kb
  const char* zbase = (const char*)z2 + (size_t)(wid * 64) * 4096 +
                      h * 2048 + lrow * 64 + kb * 16;

  bf16x8 cur0 = *(const bf16x8*)(zbase + 0 * 1024);
  bf16x8 cur1 = *(const bf16x8*)(zbase + 1 * 1024);
  u32x4 bits0 = *(const u32x4*)pr0;
  u32x4 bits1 = *(const u32x4*)pr1;
  u32x4 bits2 = *(const u32x4*)pr2;
  u32x4 bits3 = *(const u32x4*)pr3;

  for (int it = 0; it < 16; ++it) {
    // bits prefetch, one iter ahead (tail covered by 64 B ws slack)
    u32x4 nb0 = *(const u32x4*)(pr0 + 4);
    u32x4 nb1 = *(const u32x4*)(pr1 + 4);
    u32x4 nb2 = *(const u32x4*)(pr2 + 4);
    u32x4 nb3 = *(const u32x4*)(pr3 + 4);
#pragma unroll
    for (int s = 0; s < 4; ++s) {
      // next chunk's two half-fragments (tail lands in mapped packed; unused)
      const char* zn = zbase + (s + 1) * 4096;
      bf16x8 n0 = *(const bf16x8*)(zn + 0 * 1024);
      bf16x8 n1 = *(const bf16x8*)(zn + 1 * 1024);

      bf16x8 a0 = decode8(bits0[s] >> sh);
      acc[0][0] = __builtin_amdgcn_mfma_f32_16x16x32_bf16(a0, cur0, acc[0][0], 0, 0, 0);
      acc[0][1] = __builtin_amdgcn_mfma_f32_16x16x32_bf16(a0, cur1, acc[0][1], 0, 0, 0);
      bf16x8 a1 = decode8(bits1[s] >> sh);
      acc[1][0] = __builtin_amdgcn_mfma_f32_16x16x32_bf16(a1, cur0, acc[1][0], 0, 0, 0);
      acc[1][1] = __builtin_amdgcn_mfma_f32_16x16x32_bf16(a1, cur1, acc[1][1], 0, 0, 0);
      bf16x8 a2 = decode8(bits2[s] >> sh);
      acc[2][0] = __builtin_amdgcn_mfma_f32_16x16x32_bf16(a2, cur0, acc[2][0], 0, 0, 0);
      acc[2][1] = __builtin_amdgcn_mfma_f32_16x16x32_bf16(a2, cur1, acc[2][1], 0, 0, 0);
      bf16x8 a3 = decode8(bits3[s] >> sh);
      acc[3][0] = __builtin_amdgcn_mfma_f32_16x16x32_bf16(a3, cur0, acc[3][0], 0, 0, 0);
      acc[3][1] = __builtin_amdgcn_mfma_f32_16x16x32_bf16(a3, cur1, acc[3][1], 0, 0, 0);

      cur0 = n0; cur1 = n1;
    }
    bits0 = nb0; bits1 = nb1; bits2 = nb2; bits3 = nb3;
    pr0 += 4; pr1 += 4; pr2 += 4; pr3 += 4;
    zbase += 16384;
  }

  // two-phase split-K reduction (same grouping/order as R7):
  // row = m*16 + kb*4 + r, col(local) = n*16 + lrow
  if (wid < 4) {
#pragma unroll
    for (int m = 0; m < 4; ++m)
#pragma unroll
      for (int n = 0; n < 2; ++n)
#pragma unroll
        for (int r = 0; r < 4; ++r)
          red[wid][m * 16 + kb * 4 + r][n * 16 + lrow] = acc[m][n][r];
  }
  __syncthreads();
  if (wid >= 4) {
#pragma unroll
    for (int m = 0; m < 4; ++m)
#pragma unroll
      for (int n = 0; n < 2; ++n)
#pragma unroll
        for (int r = 0; r < 4; ++r)
          red[wid - 4][m * 16 + kb * 4 + r][n * 16 + lrow] += acc[m][n][r];
  }
  __syncthreads();

  // epilogue: 512 threads cover 64 rows x 32 local cols
  const int c = tid & 31;            // local col
  const int rg = tid >> 5;           // 0..15, 4 rows each
  const int gc = h * 32 + c;         // global col
  const float bc = bias[gc];
#pragma unroll
  for (int rr = 0; rr < 4; ++rr) {
    int r = rg * 4 + rr;
    int i = i0 + r;
    float s = red[0][r][c] + red[1][r][c] + red[2][r][c] + red[3][r][c];
    float o = dinv[i] * (s + bf2f(z_rm[(size_t)i * GF + gc])) + bc;
    out[(size_t)i * GF + gc] = fmaxf(o, 0.f);
  }
}

// ---------------------------------------------------------------------------
extern "C" void kernel_launch(void* const* d_in, const int* in_sizes, int n_in,
                              void* d_out, int out_size, void* d_ws, size_t ws_size,
                              hipStream_t stream) {
  const float* x = (const float*)d_in[0];
  const float* adj = (const float*)d_in[1];
  const float* W = (const float*)d_in[2];
  const float* bias = (const float*)d_in[3];
  float* out = (float*)d_out;

  char* ws = (char*)d_ws;
  float* deg = (float*)ws;                                        // 64 KB
  float* dinv = (float*)(ws + 65536);                             // 64 KB
  unsigned short* z_rm = (unsigned short*)(ws + 131072);          // 2 MB
  unsigned short* z2 = (unsigned short*)(ws + 131072 + 2097152);  // 2 MB chunk-tiled
  unsigned int* packed = (unsigned int*)(ws + 131072 + 4194304);  // 32 MB + 64 B slack
  if (ws_size < 37879872u) return;

  hipMemsetAsync(deg, 0, GN * sizeof(float), stream);
  k_pack<<<dim3(512), dim3(256), 0, stream>>>(adj, deg, packed);
  k_z<<<dim3(GN / 64), dim3(256), 0, stream>>>(x, W, deg, dinv, z_rm, z2);
  k_spmm<<<dim3(512), dim3(512), 0, stream>>>(packed, z2, z_rm, dinv, bias, out);
}

// Round 13
// 268.335 us; speedup vs baseline: 1.1853x; 1.0540x over previous
//
#include <hip/hip_runtime.h>
#include <cstdint>
#include <cstddef>

#define GN 16384          // nodes
#define GF 64             // features
#define NW (GN / 32)      // 512 dwords per packed bit-row

typedef __bf16 bf16x8 __attribute__((ext_vector_type(8)));
typedef float f32x4 __attribute__((ext_vector_type(4)));
typedef unsigned int u32x4 __attribute__((ext_vector_type(4)));

// R2/R6/R7-validated cheap decode.
__device__ __forceinline__ bf16x8 decode8(unsigned int b) {
  unsigned int t = (b & 0xffu) * 0x8001u;
  u32x4 r;
  r[0] = (t & 0x00010001u) * 0x3F80u;
  r[1] = ((t >> 2) & 0x00010001u) * 0x3F80u;
  r[2] = ((t >> 4) & 0x00010001u) * 0x3F80u;
  r[3] = ((t >> 6) & 0x00010001u) * 0x3F80u;
  return __builtin_bit_cast(bf16x8, r);
}

__device__ __forceinline__ unsigned short f2bf(float v) {  // RNE f32->bf16
  unsigned int u = __builtin_bit_cast(unsigned int, v);
  u += 0x7fffu + ((u >> 16) & 1u);
  return (unsigned short)(u >> 16);
}

__device__ __forceinline__ float bf2f(unsigned short s) {
  return __builtin_bit_cast(float, (unsigned int)s << 16);
}

// ---------------------------------------------------------------------------
// K1 v6: R7 structure; atomics replaced by plain partial-count stores.
// cnt_part[jb][col] = popcount of slab jb for column col (exact int in f32).
// No memset needed anywhere anymore.
// ---------------------------------------------------------------------------
__global__ __launch_bounds__(256) void k_pack(const float* __restrict__ adj,
                                              float* __restrict__ cnt_part,
                                              unsigned int* __restrict__ packed) {
  const int cb = blockIdx.x >> 5;
  const int jb = blockIdx.x & 31;
  const int col0 = cb * 1024 + threadIdx.x * 4;
  const int j0 = jb * 512;
  int cnt0 = 0, cnt1 = 0, cnt2 = 0, cnt3 = 0;

  u32x4 vv0[4], vv1[4], vv2[4], vv3[4];

#pragma unroll
  for (int seg = 0; seg < 4; ++seg) {
#pragma unroll
    for (int q = 0; q < 4; ++q) {
      unsigned int w0 = 0, w1 = 0, w2 = 0, w3 = 0;
      const float* base = adj + (size_t)(j0 + seg * 128 + q * 32) * GN + col0;
#pragma unroll 8
      for (int b = 0; b < 32; ++b) {
        f32x4 a = *(const f32x4*)(base + (size_t)b * GN);
        unsigned int m = 1u << b;
        if (a.x != 0.f) w0 |= m;
        if (a.y != 0.f) w1 |= m;
        if (a.z != 0.f) w2 |= m;
        if (a.w != 0.f) w3 |= m;
      }
      vv0[seg][q] = w0; vv1[seg][q] = w1; vv2[seg][q] = w2; vv3[seg][q] = w3;
      cnt0 += __popc(w0); cnt1 += __popc(w1); cnt2 += __popc(w2); cnt3 += __popc(w3);
    }
  }
  unsigned int* p0 = packed + (size_t)(col0 + 0) * NW + (size_t)jb * 16;
  unsigned int* p1 = packed + (size_t)(col0 + 1) * NW + (size_t)jb * 16;
  unsigned int* p2 = packed + (size_t)(col0 + 2) * NW + (size_t)jb * 16;
  unsigned int* p3 = packed + (size_t)(col0 + 3) * NW + (size_t)jb * 16;
#pragma unroll
  for (int seg = 0; seg < 4; ++seg) *(u32x4*)(p0 + seg * 4) = vv0[seg];
#pragma unroll
  for (int seg = 0; seg < 4; ++seg) *(u32x4*)(p1 + seg * 4) = vv1[seg];
#pragma unroll
  for (int seg = 0; seg < 4; ++seg) *(u32x4*)(p2 + seg * 4) = vv2[seg];
#pragma unroll
  for (int seg = 0; seg < 4; ++seg) *(u32x4*)(p3 + seg * 4) = vv3[seg];

  // coalesced 16 B per thread, no atomics
  f32x4 c = {(float)cnt0, (float)cnt1, (float)cnt2, (float)cnt3};
  *(f32x4*)(cnt_part + (size_t)jb * GN + col0) = c;
}

// ---------------------------------------------------------------------------
// K2 v2: deg reconstructed from 32 partials (exact integers -> bit-identical
// dinv). Otherwise identical to R4-R12.
// ---------------------------------------------------------------------------
__global__ __launch_bounds__(256) void k_z(const float* __restrict__ x,
                                           const float* __restrict__ W,
                                           const float* __restrict__ cnt_part,
                                           float* __restrict__ dinv,
                                           unsigned short* __restrict__ z_rm,
                                           unsigned short* __restrict__ z2) {
  __shared__ float Wl[64][64];
  __shared__ float xl[64][64];
  __shared__ float degl[64];  // deg + 1 (self-loop) for this block's 64 nodes
  const int tid = threadIdx.x;
  const int f = tid & 63;
  const int w = tid >> 6;
  const int rowB = blockIdx.x * 64;

  for (int idx = tid; idx < 4096; idx += 256) {
    Wl[idx >> 6][idx & 63] = W[idx];
    xl[idx >> 6][idx & 63] = x[(size_t)rowB * 64 + idx];
  }
  if (tid < 64) {
    float s = 1.0f;  // self-loop
    for (int jb = 0; jb < 32; ++jb) s += cnt_part[(size_t)jb * GN + rowB + tid];
    degl[tid] = s;
  }
  __syncthreads();

  float acc[16];
#pragma unroll
  for (int r = 0; r < 16; ++r) acc[r] = 0.f;
  for (int k = 0; k < 64; ++k) {
    float wk = Wl[k][f];
#pragma unroll
    for (int r = 0; r < 16; ++r) acc[r] = fmaf(xl[w * 16 + r][k], wk, acc[r]);
  }

  const int row0 = rowB + w * 16;
  if (f < 16) {
    int row = row0 + f;
    dinv[row] = 1.0f / sqrtf(degl[w * 16 + f]);
  }

  unsigned short zs[16];
#pragma unroll
  for (int r = 0; r < 16; ++r) {
    int row = row0 + r;
    float di = 1.0f / sqrtf(degl[w * 16 + r]);
    unsigned short zb = f2bf(di * acc[r]);
    zs[r] = zb;
    z_rm[(size_t)row * GF + f] = zb;
  }
  unsigned int p[8];
#pragma unroll
  for (int i = 0; i < 8; ++i)
    p[i] = (unsigned int)zs[2 * i] | ((unsigned int)zs[2 * i + 1] << 16);
  char* dst = (char*)z2 + (size_t)((rowB >> 5) + (w >> 1)) * 4096 + f * 64 + (w & 1) * 32;
  u32x4 lo = {p[0], p[1], p[2], p[3]};
  u32x4 hi = {p[4], p[5], p[6], p[7]};
  *(u32x4*)dst = lo;
  *(u32x4*)(dst + 16) = hi;
}

// ---------------------------------------------------------------------------
// K3 v9: EXACT R7 v5 structure; ONE change: all 8 bits-load sites are
// __builtin_nontemporal_load (single-use 32 MB stream must not evict the
// 2 MB z2 set from per-XCD L2). VGPR-neutral; numerics identical.
// ---------------------------------------------------------------------------
__global__ __launch_bounds__(512) void k_spmm(const unsigned int* __restrict__ packed,
                                              const unsigned short* __restrict__ z2,
                                              const unsigned short* __restrict__ z_rm,
                                              const float* __restrict__ dinv,
                                              const float* __restrict__ bias,
                                              float* __restrict__ out) {
  __shared__ float red[4][64][64];  // 64 KB
  const int i0 = blockIdx.x * 64;
  const int tid = threadIdx.x;
  const int wid = tid >> 6, lane = tid & 63;
  const int lrow = lane & 15, kb = lane >> 4;
  const int sh = kb * 8;

  f32x4 acc[4][4];
#pragma unroll
  for (int m = 0; m < 4; ++m)
#pragma unroll
    for (int n = 0; n < 4; ++n) acc[m][n] = (f32x4){0.f, 0.f, 0.f, 0.f};

  const unsigned int* pr0 = packed + (size_t)(i0 + 0 * 16 + lrow) * NW + wid * 64;
  const unsigned int* pr1 = packed + (size_t)(i0 + 1 * 16 + lrow) * NW + wid * 64;
  const unsigned int* pr2 = packed + (size_t)(i0 + 2 * 16 + lrow) * NW + wid * 64;
  const unsigned int* pr3 = packed + (size_t)(i0 + 3 * 16 + lrow) * NW + wid * 64;
  const char* zbase = (const char*)z2 + (size_t)(wid * 64) * 4096 + lrow * 64 + kb * 16;

  bf16x8 cur0 = *(const bf16x8*)(zbase + 0 * 1024);
  bf16x8 cur1 = *(const bf16x8*)(zbase + 1 * 1024);
  bf16x8 cur2 = *(const bf16x8*)(zbase + 2 * 1024);
  bf16x8 cur3 = *(const bf16x8*)(zbase + 3 * 1024);
  u32x4 bits0 = __builtin_nontemporal_load((const u32x4*)pr0);
  u32x4 bits1 = __builtin_nontemporal_load((const u32x4*)pr1);
  u32x4 bits2 = __builtin_nontemporal_load((const u32x4*)pr2);
  u32x4 bits3 = __builtin_nontemporal_load((const u32x4*)pr3);

  for (int it = 0; it < 16; ++it) {
    u32x4 nb0 = __builtin_nontemporal_load((const u32x4*)(pr0 + 4));
    u32x4 nb1 = __builtin_nontemporal_load((const u32x4*)(pr1 + 4));
    u32x4 nb2 = __builtin_nontemporal_load((const u32x4*)(pr2 + 4));
    u32x4 nb3 = __builtin_nontemporal_load((const u32x4*)(pr3 + 4));
#pragma unroll
    for (int s = 0; s < 4; ++s) {
      const char* zn = zbase + (s + 1) * 4096;
      bf16x8 n0 = *(const bf16x8*)(zn + 0 * 1024);
      bf16x8 n1 = *(const bf16x8*)(zn + 1 * 1024);
      bf16x8 n2 = *(const bf16x8*)(zn + 2 * 1024);
      bf16x8 n3 = *(const bf16x8*)(zn + 3 * 1024);

      bf16x8 a0 = decode8(bits0[s] >> sh);
      acc[0][0] = __builtin_amdgcn_mfma_f32_16x16x32_bf16(a0, cur0, acc[0][0], 0, 0, 0);
      acc[0][1] = __builtin_amdgcn_mfma_f32_16x16x32_bf16(a0, cur1, acc[0][1], 0, 0, 0);
      acc[0][2] = __builtin_amdgcn_mfma_f32_16x16x32_bf16(a0, cur2, acc[0][2], 0, 0, 0);
      acc[0][3] = __builtin_amdgcn_mfma_f32_16x16x32_bf16(a0, cur3, acc[0][3], 0, 0, 0);
      bf16x8 a1 = decode8(bits1[s] >> sh);
      acc[1][0] = __builtin_amdgcn_mfma_f32_16x16x32_bf16(a1, cur0, acc[1][0], 0, 0, 0);
      acc[1][1] = __builtin_amdgcn_mfma_f32_16x16x32_bf16(a1, cur1, acc[1][1], 0, 0, 0);
      acc[1][2] = __builtin_amdgcn_mfma_f32_16x16x32_bf16(a1, cur2, acc[1][2], 0, 0, 0);
      acc[1][3] = __builtin_amdgcn_mfma_f32_16x16x32_bf16(a1, cur3, acc[1][3], 0, 0, 0);
      bf16x8 a2 = decode8(bits2[s] >> sh);
      acc[2][0] = __builtin_amdgcn_mfma_f32_16x16x32_bf16(a2, cur0, acc[2][0], 0, 0, 0);
      acc[2][1] = __builtin_amdgcn_mfma_f32_16x16x32_bf16(a2, cur1, acc[2][1], 0, 0, 0);
      acc[2][2] = __builtin_amdgcn_mfma_f32_16x16x32_bf16(a2, cur2, acc[2][2], 0, 0, 0);
      acc[2][3] = __builtin_amdgcn_mfma_f32_16x16x32_bf16(a2, cur3, acc[2][3], 0, 0, 0);
      bf16x8 a3 = decode8(bits3[s] >> sh);
      acc[3][0] = __builtin_amdgcn_mfma_f32_16x16x32_bf16(a3, cur0, acc[3][0], 0, 0, 0);
      acc[3][1] = __builtin_amdgcn_mfma_f32_16x16x32_bf16(a3, cur1, acc[3][1], 0, 0, 0);
      acc[3][2] = __builtin_amdgcn_mfma_f32_16x16x32_bf16(a3, cur2, acc[3][2], 0, 0, 0);
      acc[3][3] = __builtin_amdgcn_mfma_f32_16x16x32_bf16(a3, cur3, acc[3][3], 0, 0, 0);

      cur0 = n0; cur1 = n1; cur2 = n2; cur3 = n3;
    }
    bits0 = nb0; bits1 = nb1; bits2 = nb2; bits3 = nb3;
    pr0 += 4; pr1 += 4; pr2 += 4; pr3 += 4;
    zbase += 16384;
  }

  if (wid < 4) {
#pragma unroll
    for (int m = 0; m < 4; ++m)
#pragma unroll
      for (int n = 0; n < 4; ++n)
#pragma unroll
        for (int r = 0; r < 4; ++r)
          red[wid][m * 16 + kb * 4 + r][n * 16 + lrow] = acc[m][n][r];
  }
  __syncthreads();
  if (wid >= 4) {
#pragma unroll
    for (int m = 0; m < 4; ++m)
#pragma unroll
      for (int n = 0; n < 4; ++n)
#pragma unroll
        for (int r = 0; r < 4; ++r)
          red[wid - 4][m * 16 + kb * 4 + r][n * 16 + lrow] += acc[m][n][r];
  }
  __syncthreads();

  const int c = tid & 63;
  const int rg = tid >> 6;
  const float bc = bias[c];
#pragma unroll
  for (int rr = 0; rr < 8; ++rr) {
    int r = rg * 8 + rr;
    int i = i0 + r;
    float s = red[0][r][c] + red[1][r][c] + red[2][r][c] + red[3][r][c];
    float o = dinv[i] * (s + bf2f(z_rm[(size_t)i * GF + c])) + bc;
    out[(size_t)i * GF + c] = fmaxf(o, 0.f);
  }
}

// ---------------------------------------------------------------------------
extern "C" void kernel_launch(void* const* d_in, const int* in_sizes, int n_in,
                              void* d_out, int out_size, void* d_ws, size_t ws_size,
                              hipStream_t stream) {
  const float* x = (const float*)d_in[0];
  const float* adj = (const float*)d_in[1];
  const float* W = (const float*)d_in[2];
  const float* bias = (const float*)d_in[3];
  float* out = (float*)d_out;

  char* ws = (char*)d_ws;
  float* cnt_part = (float*)ws;                                     // 2 MB [32][16384]
  float* dinv = (float*)(ws + 2097152);                             // 64 KB
  unsigned short* z_rm = (unsigned short*)(ws + 2097152 + 65536);   // 2 MB
  unsigned short* z2 = (unsigned short*)(ws + 4194304 + 65536);     // 2 MB chunk-tiled
  unsigned int* packed = (unsigned int*)(ws + 6291456 + 65536);     // 32 MB + 64 B slack
  // need: 6 MB + 64 KB + 32 MB + 64 B = 39,911,488 B
  if (ws_size < 39911488u) return;

  k_pack<<<dim3(512), dim3(256), 0, stream>>>(adj, cnt_part, packed);
  k_z<<<dim3(GN / 64), dim3(256), 0, stream>>>(x, W, cnt_part, dinv, z_rm, z2);
  k_spmm<<<dim3(GN / 64), dim3(512), 0, stream>>>(packed, z2, z_rm, dinv, bias, out);
}